// Round 4
// baseline (458.062 us; speedup 1.0000x reference)
//
#include <hip/hip_runtime.h>
#include <stdint.h>

typedef unsigned short u16;
typedef __bf16 bf16x8 __attribute__((ext_vector_type(8)));
typedef short s16x8 __attribute__((ext_vector_type(8)));
typedef short s16x4 __attribute__((ext_vector_type(4)));
typedef float f32x4 __attribute__((ext_vector_type(4)));

__device__ __forceinline__ u16 f2bf(float f) {
  uint32_t u = __builtin_bit_cast(uint32_t, f);
  u += 0x7fffu + ((u >> 16) & 1u);
  return (u16)(u >> 16);
}
__device__ __forceinline__ float bf2f(u16 h) {
  uint32_t u = ((uint32_t)h) << 16;
  return __builtin_bit_cast(float, u);
}

// async global->LDS, 16B per lane, wave-uniform LDS base + lane*16
__device__ __forceinline__ void gl16(const u16* g, u16* l) {
  __builtin_amdgcn_global_load_lds(
      (const __attribute__((address_space(1))) void*)g,
      (__attribute__((address_space(3))) void*)l, 16, 0, 0);
}

// s_barrier that is also a compiler memory fence (pins LDS op ordering at IR level)
__device__ __forceinline__ void barf() {
  asm volatile("s_barrier" ::: "memory");
}

// ---------------- input converts (x and x0 in one kernel) ----------------
__global__ void cvt_in2(const float* __restrict__ a, const float* __restrict__ b,
                        u16* __restrict__ da, u16* __restrict__ db, long n8each) {
  long stride = (long)gridDim.x * blockDim.x;
  long total = 2 * n8each;
  for (long i = (long)blockIdx.x * blockDim.x + threadIdx.x; i < total; i += stride) {
    const float* src = (i < n8each) ? a + i * 8 : b + (i - n8each) * 8;
    u16* dst = (i < n8each) ? da + i * 8 : db + (i - n8each) * 8;
    const f32x4* s = (const f32x4*)src;
    f32x4 v0 = s[0], v1 = s[1];
    s16x8 o;
#pragma unroll
    for (int j = 0; j < 4; ++j) o[j] = (short)f2bf(v0[j]);
#pragma unroll
    for (int j = 0; j < 4; ++j) o[4 + j] = (short)f2bf(v1[j]);
    *(s16x8*)dst = o;
  }
}

__global__ void cvt_flat8(const float* __restrict__ src, u16* __restrict__ dst,
                          long n8, float scale) {
  long stride = (long)gridDim.x * blockDim.x;
  for (long i = (long)blockIdx.x * blockDim.x + threadIdx.x; i < n8; i += stride) {
    const f32x4* s = (const f32x4*)(src + i * 8);
    f32x4 a = s[0], b = s[1];
    s16x8 o;
#pragma unroll
    for (int j = 0; j < 4; ++j) o[j] = (short)f2bf(a[j] * scale);
#pragma unroll
    for (int j = 0; j < 4; ++j) o[4 + j] = (short)f2bf(b[j] * scale);
    *(s16x8*)(dst + i * 8) = o;
  }
}

// ---------------- weight prep: all weights -> bf16 (+zero padding) ----------------
__global__ void prep_w(const float* __restrict__ c_wg, const float* __restrict__ c_wp,
                       const float* __restrict__ p_wg, const float* __restrict__ p_wp,
                       const float* __restrict__ c_wt, const float* __restrict__ p_wt,
                       const float* __restrict__ c_ww, const float* __restrict__ p_ww,
                       u16* __restrict__ wcat, u16* __restrict__ wt_c,
                       u16* __restrict__ wt_p, u16* __restrict__ ww_c,
                       u16* __restrict__ ww_p) {
  const int C0 = 1280 * 768 / 4;
  const int C1 = C0 + 384 * 768 / 4;
  const int C2 = C1 + 256 * 768 / 4;
  const int C3 = C2 + 768 * 384 / 4;
  const int C4 = C3 + 768 * 256 / 4;
  int stride = gridDim.x * blockDim.x;
  for (int i = blockIdx.x * blockDim.x + threadIdx.x; i < C4; i += stride) {
    const float* src = nullptr;
    u16* dst;
    if (i < C0) {
      int e = i * 4;
      dst = wcat + e;
      int r = e / 768;
      if (r < 384) src = c_wg + e;
      else if (r < 768) src = c_wp + e - 384 * 768;
      else if (r < 960) src = p_wg + e - 768 * 768;
      else if (r < 1024) src = nullptr;
      else if (r < 1216) src = p_wp + e - 1024 * 768;
      else src = nullptr;
    } else if (i < C1) {
      int e = (i - C0) * 4; dst = wt_c + e; src = c_wt + e;
    } else if (i < C2) {
      int e = (i - C1) * 4; dst = wt_p + e;
      src = (e / 768 < 192) ? p_wt + e : nullptr;
    } else if (i < C3) {
      int e = (i - C2) * 4; dst = ww_c + e; src = c_ww + e;
    } else {
      int e = (i - C3) * 4; dst = ww_p + e;
      int r = e >> 8, c = e & 255;
      src = (c < 192) ? p_ww + r * 192 + c : nullptr;
    }
    s16x4 o;
    if (src) {
      f32x4 v = *(const f32x4*)src;
#pragma unroll
      for (int j = 0; j < 4; ++j) o[j] = (short)f2bf(v[j]);
    } else {
      o = s16x4{0, 0, 0, 0};
    }
    *(s16x4*)dst = o;
  }
}

// biasb[1920] + zero sums[0..3071]
__global__ void prep_b(const float* __restrict__ c_bg, const float* __restrict__ c_bp,
                       const float* __restrict__ p_bg, const float* __restrict__ p_bp,
                       const float* __restrict__ c_bt, const float* __restrict__ p_bt,
                       float* __restrict__ biasb, float* __restrict__ sums) {
  int i = blockIdx.x * blockDim.x + threadIdx.x;
  if (i < 1920) {
    float v = 0.f;
    if (i < 384) v = c_bg[i];
    else if (i < 768) v = c_bp[i - 384];
    else if (i < 960) v = p_bg[i - 768];
    else if (i < 1024) v = 0.f;
    else if (i < 1216) v = p_bp[i - 1024];
    else if (i < 1280) v = 0.f;
    else if (i < 1664) v = c_bt[i - 1280];
    else if (i < 1856) v = p_bt[i - 1664];
    biasb[i] = v;
  } else if (i < 1920 + 3072) {
    sums[i - 1920] = 0.f;
  }
}

// ======== big NT GEMM: 256x256 tile, BK=32, 8 waves, 4-slot LDS ring ========
// C[M,N] = A[M,K] * B[N,K]^T (+ row bias), optional BN col sums.
// Deep pipeline: tiles T,T+1,T+2 in flight; counted vmcnt(8) once per tile.
template <int BIAS, int SUMS>
__global__ __launch_bounds__(512) void gemm_nt_big(
    const u16* __restrict__ A, const u16* __restrict__ B, void* __restrict__ Cv,
    const float* __restrict__ bias, float* __restrict__ sums,
    int ntiles, long lda, long ldb, long ldc, int K,
    long aBatch, long bBatch, long cBatch) {
  __shared__ u16 As[4][256 * 32];  // 4 slots x 16KB
  __shared__ u16 Bs[4][256 * 32];  // total 128KB

  const int bm = blockIdx.x / ntiles;
  const int bn = blockIdx.x % ntiles;
  const int bb = blockIdx.y;
  const int nt = K >> 5;  // K-tiles of 32

  const u16* Ab = A + (long)bb * aBatch + (long)bm * 256 * lda;
  const u16* Bb = B + (long)bb * bBatch + (long)bn * 256 * ldb;

  const int t = threadIdx.x;
  const int w = t >> 6;   // 0..7
  const int l = t & 63;
  const int wr = w >> 2;  // 0..1 (M half)
  const int wc = w & 3;   // 0..3 (N quarter)

  // staging: inst i covers rows [i*128, i*128+128); wave w rows [i*128+w*16, +16)
  // lane l -> row +(l>>2), 16B chunk l&3. LDS dest = slot + (i*8+w)*1024B + l*16.
  const int srow = w * 16 + (l >> 2);
  const long aoff0 = (long)srow * lda + (l & 3) * 8;
  const long aoff1 = (long)(128 + srow) * lda + (l & 3) * 8;
  const long boff0 = (long)srow * ldb + (l & 3) * 8;
  const long boff1 = (long)(128 + srow) * ldb + (l & 3) * 8;

#define STAGE_A(T, BUF)                                   \
  gl16(Ab + aoff0 + (long)(T) * 32, &As[BUF][w * 512]);   \
  gl16(Ab + aoff1 + (long)(T) * 32, &As[BUF][(8 + w) * 512]);
#define STAGE_B(T, BUF)                                   \
  gl16(Bb + boff0 + (long)(T) * 32, &Bs[BUF][w * 512]);   \
  gl16(Bb + boff1 + (long)(T) * 32, &Bs[BUF][(8 + w) * 512]);

  f32x4 acc[8][4] = {};

  // prologue: stage tiles 0,1,2 (12 gl16/wave); wait tile 0 (keep 8 in flight)
  STAGE_A(0, 0); STAGE_B(0, 0);
  if (nt > 1) { STAGE_A(1, 1); STAGE_B(1, 1); }
  if (nt > 2) { STAGE_A(2, 2); STAGE_B(2, 2); }
  if (nt > 2)      asm volatile("s_waitcnt vmcnt(8)" ::: "memory");
  else if (nt > 1) asm volatile("s_waitcnt vmcnt(4)" ::: "memory");
  else             asm volatile("s_waitcnt vmcnt(0)" ::: "memory");
  barf();

  const int kq = (l >> 4) * 8;          // u16 k-offset within row
  const int ar = wr * 128 + (l & 15);   // A row base for fragments
  const int br = wc * 64 + (l & 15);    // B row base

  for (int tt = 0; tt < nt; ++tt) {
    const int cur = tt & 3;
    const int pf = (tt + 3) & 3;
    const bool do_pf = (tt + 3) < nt;

    // ---- phase 0: B frags + A frags(m0..3); stage A of tile tt+3 ----
    bf16x8 bfr[4], af[4];
#pragma unroll
    for (int ni = 0; ni < 4; ++ni)
      bfr[ni] = __builtin_bit_cast(
          bf16x8, *(const s16x8*)(&Bs[cur][(br + ni * 16) * 32 + kq]));
#pragma unroll
    for (int mi = 0; mi < 4; ++mi)
      af[mi] = __builtin_bit_cast(
          bf16x8, *(const s16x8*)(&As[cur][(ar + mi * 16) * 32 + kq]));
    if (do_pf) { STAGE_A(tt + 3, pf); }
    barf();
    __builtin_amdgcn_s_setprio(1);
#pragma unroll
    for (int mi = 0; mi < 4; ++mi)
#pragma unroll
      for (int ni = 0; ni < 4; ++ni)
        acc[mi][ni] = __builtin_amdgcn_mfma_f32_16x16x32_bf16(
            af[mi], bfr[ni], acc[mi][ni], 0, 0, 0);
    __builtin_amdgcn_s_setprio(0);
    barf();

    // ---- phase 1: A frags(m4..7); stage B of tile tt+3 ----
    bf16x8 ag[4];
#pragma unroll
    for (int mi = 0; mi < 4; ++mi)
      ag[mi] = __builtin_bit_cast(
          bf16x8, *(const s16x8*)(&As[cur][(ar + 64 + mi * 16) * 32 + kq]));
    if (do_pf) { STAGE_B(tt + 3, pf); }
    barf();
    __builtin_amdgcn_s_setprio(1);
#pragma unroll
    for (int mi = 0; mi < 4; ++mi)
#pragma unroll
      for (int ni = 0; ni < 4; ++ni)
        acc[4 + mi][ni] = __builtin_amdgcn_mfma_f32_16x16x32_bf16(
            ag[mi], bfr[ni], acc[4 + mi][ni], 0, 0, 0);
    __builtin_amdgcn_s_setprio(0);
    // counted wait for NEXT tile (retire tt+1's 4 loads; keep rest in flight)
    if (tt + 4 <= nt)      asm volatile("s_waitcnt vmcnt(8)" ::: "memory");
    else if (tt + 3 == nt) asm volatile("s_waitcnt vmcnt(4)" ::: "memory");
    else if (tt + 2 == nt) asm volatile("s_waitcnt vmcnt(0)" ::: "memory");
    barf();
  }
#undef STAGE_A
#undef STAGE_B
  __builtin_amdgcn_sched_barrier(0);

  const long crow0 = (long)bm * 256 + wr * 128;
  const long ccol0 = (long)bn * 256 + wc * 64;
  u16* C = (u16*)Cv + (long)bb * cBatch;
#pragma unroll
  for (int mi = 0; mi < 8; ++mi)
#pragma unroll
    for (int j = 0; j < 4; ++j) {
      long row = crow0 + mi * 16 + (l >> 4) * 4 + j;
      float rb = (BIAS == 1) ? bias[row] : 0.f;
#pragma unroll
      for (int ni = 0; ni < 4; ++ni) {
        long col = ccol0 + ni * 16 + (l & 15);
        C[row * ldc + col] = f2bf(acc[mi][ni][j] + rb);
      }
    }

  if (SUMS) {
#pragma unroll
    for (int ni = 0; ni < 4; ++ni) {
      float s = 0.f, q = 0.f;
#pragma unroll
      for (int mi = 0; mi < 8; ++mi)
#pragma unroll
        for (int j = 0; j < 4; ++j) {
          float v = acc[mi][ni][j];
          s += v;
          q += v * v;
        }
      s += __shfl_xor(s, 16);
      q += __shfl_xor(q, 16);
      s += __shfl_xor(s, 32);
      q += __shfl_xor(q, 32);
      if (l < 16) {
        long col = ccol0 + ni * 16 + l;
        atomicAdd(&sums[col], s);
        atomicAdd(&sums[768 + col], q);
      }
    }
  }
}

// ---------------- generic NT GEMM (128x128, 4 waves) — small/odd shapes ----------------
template <int BIAS, int OUT_ATOMIC, int SUMS>
__global__ __launch_bounds__(256) void gemm_nt(
    const u16* __restrict__ A, const u16* __restrict__ B, void* __restrict__ Cv,
    const float* __restrict__ bias, float* __restrict__ sums,
    int ntiles, long lda, long ldb, long ldc, int K,
    long aBatch, long bBatch, long cBatch) {
  __shared__ u16 As[2][128 * 32];
  __shared__ u16 Bs[2][128 * 32];

  const int bm = blockIdx.x / ntiles;
  const int bn = blockIdx.x % ntiles;
  const int bb = blockIdx.y;
  const int kChunk = K / gridDim.z;
  const long k0base = (long)blockIdx.z * kChunk;
  const int nt = kChunk >> 5;

  const u16* Ab = A + (long)bb * aBatch + (long)bm * 128 * lda + k0base;
  const u16* Bb = B + (long)bb * bBatch + (long)bn * 128 * ldb + k0base;

  const int t = threadIdx.x;
  const int w = t >> 6;
  const int l = t & 63;
  const int wr = w >> 1, wc = w & 1;

  const long aoff = (long)(32 * w + (l >> 2)) * lda + (l & 3) * 8;
  const long boff = (long)(32 * w + (l >> 2)) * ldb + (l & 3) * 8;

  f32x4 acc[4][4] = {};

  gl16(Ab + aoff, &As[0][(32 * w) * 32]);
  gl16(Ab + aoff + 16 * lda, &As[0][(32 * w + 16) * 32]);
  gl16(Bb + boff, &Bs[0][(32 * w) * 32]);
  gl16(Bb + boff + 16 * ldb, &Bs[0][(32 * w + 16) * 32]);
  if (nt > 1) {
    gl16(Ab + aoff + 32, &As[1][(32 * w) * 32]);
    gl16(Ab + aoff + 16 * lda + 32, &As[1][(32 * w + 16) * 32]);
    gl16(Bb + boff + 32, &Bs[1][(32 * w) * 32]);
    gl16(Bb + boff + 16 * ldb + 32, &Bs[1][(32 * w + 16) * 32]);
  }

  for (int tt = 0; tt < nt; ++tt) {
    const int cur = tt & 1;
    if (tt + 1 < nt)
      asm volatile("s_waitcnt vmcnt(4)" ::: "memory");
    else
      asm volatile("s_waitcnt vmcnt(0)" ::: "memory");
    __builtin_amdgcn_s_barrier();

    const int kq = (l >> 4) * 8;
    bf16x8 af[4], bfr[4];
#pragma unroll
    for (int mi = 0; mi < 4; ++mi)
      af[mi] = __builtin_bit_cast(
          bf16x8, *(const s16x8*)(&As[cur][(wr * 64 + mi * 16 + (l & 15)) * 32 + kq]));
#pragma unroll
    for (int ni = 0; ni < 4; ++ni)
      bfr[ni] = __builtin_bit_cast(
          bf16x8, *(const s16x8*)(&Bs[cur][(wc * 64 + ni * 16 + (l & 15)) * 32 + kq]));
#pragma unroll
    for (int mi = 0; mi < 4; ++mi)
#pragma unroll
      for (int ni = 0; ni < 4; ++ni)
        acc[mi][ni] = __builtin_amdgcn_mfma_f32_16x16x32_bf16(
            af[mi], bfr[ni], acc[mi][ni], 0, 0, 0);

    __builtin_amdgcn_s_barrier();
    if (tt + 2 < nt) {
      const long ko = (long)(tt + 2) * 32;
      gl16(Ab + aoff + ko, &As[cur][(32 * w) * 32]);
      gl16(Ab + aoff + 16 * lda + ko, &As[cur][(32 * w + 16) * 32]);
      gl16(Bb + boff + ko, &Bs[cur][(32 * w) * 32]);
      gl16(Bb + boff + 16 * ldb + ko, &Bs[cur][(32 * w + 16) * 32]);
    }
  }
  __builtin_amdgcn_sched_barrier(0);

  const long crow0 = (long)bm * 128 + wr * 64;
  const long ccol0 = (long)bn * 128 + wc * 64;

  if (OUT_ATOMIC) {
    float* C = (float*)Cv + (long)bb * cBatch;
#pragma unroll
    for (int mi = 0; mi < 4; ++mi)
#pragma unroll
      for (int j = 0; j < 4; ++j) {
        long row = crow0 + mi * 16 + (l >> 4) * 4 + j;
#pragma unroll
        for (int ni = 0; ni < 4; ++ni) {
          long col = ccol0 + ni * 16 + (l & 15);
          atomicAdd(&C[row * ldc + col], acc[mi][ni][j]);
        }
      }
  } else {
    u16* C = (u16*)Cv + (long)bb * cBatch;
#pragma unroll
    for (int mi = 0; mi < 4; ++mi)
#pragma unroll
      for (int j = 0; j < 4; ++j) {
        long row = crow0 + mi * 16 + (l >> 4) * 4 + j;
        float rb = (BIAS == 1) ? bias[row] : 0.f;
#pragma unroll
        for (int ni = 0; ni < 4; ++ni) {
          long col = ccol0 + ni * 16 + (l & 15);
          float cb = (BIAS == 2) ? bias[col] : 0.f;
          C[row * ldc + col] = f2bf(acc[mi][ni][j] + rb + cb);
        }
      }
  }

  if (SUMS) {
#pragma unroll
    for (int ni = 0; ni < 4; ++ni) {
      float s = 0.f, q = 0.f;
#pragma unroll
      for (int mi = 0; mi < 4; ++mi)
#pragma unroll
        for (int j = 0; j < 4; ++j) {
          float v = acc[mi][ni][j];
          s += v;
          q += v * v;
        }
      s += __shfl_xor(s, 16);
      q += __shfl_xor(q, 16);
      s += __shfl_xor(s, 32);
      q += __shfl_xor(q, 32);
      if (l < 16) {
        long col = ccol0 + ni * 16 + l;
        atomicAdd(&sums[col], s);
        atomicAdd(&sums[768 + col], q);
      }
    }
  }
}

// ---------------- BN ----------------
__global__ void bn_stats(const float* __restrict__ sums, const float* __restrict__ gamma,
                         const float* __restrict__ beta, float* __restrict__ stats,
                         float invN) {
  int c = threadIdx.x;
  float mu = sums[c] * invN;
  float var = sums[768 + c] * invN - mu * mu;
  float sc = gamma[c] * rsqrtf(var + 1e-5f);
  stats[c] = sc;
  stats[768 + c] = beta[c] - mu * sc;
}

template <int OUT_F32>
__global__ void bn_apply(const u16* __restrict__ pre, const u16* __restrict__ resid,
                         const float* __restrict__ stats, void* __restrict__ out,
                         long n8) {
  long stride = (long)gridDim.x * blockDim.x;
  for (long i = (long)blockIdx.x * blockDim.x + threadIdx.x; i < n8; i += stride) {
    long base = i * 8;
    int c = (int)(base % 768);
    f32x4 sc0 = *(const f32x4*)(stats + c);
    f32x4 sc1 = *(const f32x4*)(stats + c + 4);
    f32x4 sh0 = *(const f32x4*)(stats + 768 + c);
    f32x4 sh1 = *(const f32x4*)(stats + 768 + c + 4);
    s16x8 p = *(const s16x8*)(pre + base);
    s16x8 rv = *(const s16x8*)(resid + base);
    float o[8];
#pragma unroll
    for (int j = 0; j < 4; ++j)
      o[j] = bf2f((u16)p[j]) * sc0[j] + sh0[j] + bf2f((u16)rv[j]);
#pragma unroll
    for (int j = 0; j < 4; ++j)
      o[4 + j] = bf2f((u16)p[4 + j]) * sc1[j] + sh1[j] + bf2f((u16)rv[4 + j]);
    if (OUT_F32) {
      f32x4 o0, o1;
#pragma unroll
      for (int j = 0; j < 4; ++j) { o0[j] = o[j]; o1[j] = o[4 + j]; }
      f32x4* op = (f32x4*)((float*)out + base);
      op[0] = o0;
      op[1] = o1;
    } else {
      s16x8 ov;
#pragma unroll
      for (int j = 0; j < 8; ++j) ov[j] = (short)f2bf(o[j]);
      *(s16x8*)((u16*)out + base) = ov;
    }
  }
}

extern "C" void kernel_launch(void* const* d_in, const int* in_sizes, int n_in,
                              void* d_out, int out_size, void* d_ws, size_t ws_size,
                              hipStream_t stream) {
  const float* x = (const float*)d_in[0];
  const float* x0 = (const float*)d_in[1];
  const float* c_wg = (const float*)d_in[2];
  const float* c_bg = (const float*)d_in[3];
  const float* c_wt = (const float*)d_in[4];
  const float* c_bt = (const float*)d_in[5];
  const float* c_wp = (const float*)d_in[6];
  const float* c_bp = (const float*)d_in[7];
  const float* c_ww = (const float*)d_in[8];
  const float* c_gamma = (const float*)d_in[10];
  const float* c_beta = (const float*)d_in[11];
  const float* p_wg = (const float*)d_in[12];
  const float* p_bg = (const float*)d_in[13];
  const float* p_wt = (const float*)d_in[14];
  const float* p_bt = (const float*)d_in[15];
  const float* p_wp = (const float*)d_in[16];
  const float* p_bp = (const float*)d_in[17];
  const float* p_ww = (const float*)d_in[18];
  const float* p_gamma = (const float*)d_in[20];
  const float* p_beta = (const float*)d_in[21];

  char* ws = (char*)d_ws;
  const long NT = 32768;
  u16* xbf = (u16*)(ws + 0);
  u16* x0bf = (u16*)(ws + 50331648);
  u16* th = (u16*)(ws + 50331648);
  float* kvf_c = (float*)(ws + 75497472);
  float* kvf_p = (float*)(ws + 80216064);
  u16* kvb = (u16*)(ws + 82313216);
  u16* kvwT = (u16*)(ws + 84672512);
  u16* gphT = (u16*)(ws + 100663296);
  u16* wcat = (u16*)(ws + 184549376);
  u16* wt_c = (u16*)(ws + 186515456);
  u16* wt_p = (u16*)(ws + 187105280);
  u16* ww_c = (u16*)(ws + 187498496);
  u16* ww_p = (u16*)(ws + 188088320);
  float* biasb = (float*)(ws + 188481536);
  float* sums = (float*)(ws + 188489216);
  float* stats = (float*)(ws + 188501504);
  u16* zbf = xbf;
  u16* pre = gphT;

  // ---- prep ----
  cvt_in2<<<4096, 256, 0, stream>>>(x, x0, xbf, x0bf, NT * 768 / 8);
  prep_w<<<480, 256, 0, stream>>>(c_wg, c_wp, p_wg, p_wp, c_wt, p_wt, c_ww, p_ww,
                                  wcat, wt_c, wt_p, ww_c, ww_p);
  prep_b<<<20, 256, 0, stream>>>(c_bg, c_bp, p_bg, p_bp, c_bt, p_bt, biasb, sums);

  // ---- fused gphT[1280][32768] = Wcat @ x0^T (+row bias), 256^2 pipeline ----
  gemm_nt_big<1, 0><<<dim3(5 * 128, 1, 1), 512, 0, stream>>>(
      wcat, x0bf, gphT, biasb, nullptr, 128, 768, 768, 32768, 768, 0, 0, 0);
  hipMemsetAsync(kvf_c, 0, 4718592 + 2097152, stream);

  // ================= CNL (D=384) =================
  gemm_nt<2, 0, 0><<<dim3(256 * 3, 1, 1), 256, 0, stream>>>(
      xbf, wt_c, th, biasb + 1280, nullptr, 3, 768, 768, 384, 768, 0, 0, 0);
  gemm_nt<0, 1, 0><<<dim3(9, 8, 8), 256, 0, stream>>>(
      gphT + (long)384 * 32768, gphT, kvf_c, nullptr, nullptr, 3, 32768, 32768,
      384, 4096, 4096, 4096, (long)384 * 384);
  cvt_flat8<<<576, 256, 0, stream>>>(kvf_c, kvb, (long)8 * 384 * 384 / 8, 1.f / 4096.f);
  gemm_nt<0, 0, 0><<<dim3(18, 8, 1), 256, 0, stream>>>(
      ww_c, kvb, kvwT, nullptr, nullptr, 3, 384, 384, 384, 384, 0,
      (long)384 * 384, (long)768 * 384);
  gemm_nt_big<0, 1><<<dim3(48, 8, 1), 512, 0, stream>>>(
      th, kvwT, pre, nullptr, sums, 3, 384, 384, 768, 384, (long)4096 * 384,
      (long)768 * 384, (long)4096 * 768);
  bn_stats<<<1, 768, 0, stream>>>(sums, c_gamma, c_beta, stats, 1.f / 32768.f);
  bn_apply<0><<<2048, 256, 0, stream>>>(pre, xbf, stats, zbf, NT * 768 / 8);

  // ================= PNL (D=192, padded to 256) =================
  gemm_nt<2, 0, 0><<<dim3(256 * 2, 1, 1), 256, 0, stream>>>(
      zbf, wt_p, th, biasb + 1664, nullptr, 2, 768, 768, 256, 768, 0, 0, 0);
  gemm_nt<0, 1, 0><<<dim3(4, 8, 8), 256, 0, stream>>>(
      gphT + (long)1024 * 32768, gphT + (long)768 * 32768, kvf_p, nullptr, nullptr,
      2, 32768, 32768, 256, 4096, 4096, 4096, (long)256 * 256);
  cvt_flat8<<<256, 256, 0, stream>>>(kvf_p, kvb, (long)8 * 256 * 256 / 8, 1.f / 4096.f);
  gemm_nt<0, 0, 0><<<dim3(12, 8, 1), 256, 0, stream>>>(
      ww_p, kvb, kvwT, nullptr, nullptr, 2, 256, 256, 256, 256, 0,
      (long)256 * 256, (long)768 * 256);
  gemm_nt_big<0, 1><<<dim3(48, 8, 1), 512, 0, stream>>>(
      th, kvwT, pre, nullptr, sums + 1536, 3, 256, 256, 768, 256, (long)4096 * 256,
      (long)768 * 256, (long)4096 * 768);
  bn_stats<<<1, 768, 0, stream>>>(sums + 1536, p_gamma, p_beta, stats, 1.f / 32768.f);
  bn_apply<1><<<2048, 256, 0, stream>>>(pre, zbf, stats, (float*)d_out, NT * 768 / 8);
}

// Round 5
// 449.983 us; speedup vs baseline: 1.0180x; 1.0180x over previous
//
#include <hip/hip_runtime.h>
#include <stdint.h>

typedef unsigned short u16;
typedef __bf16 bf16x8 __attribute__((ext_vector_type(8)));
typedef short s16x8 __attribute__((ext_vector_type(8)));
typedef short s16x4 __attribute__((ext_vector_type(4)));
typedef float f32x4 __attribute__((ext_vector_type(4)));

__device__ __forceinline__ u16 f2bf(float f) {
  uint32_t u = __builtin_bit_cast(uint32_t, f);
  u += 0x7fffu + ((u >> 16) & 1u);
  return (u16)(u >> 16);
}
__device__ __forceinline__ float bf2f(u16 h) {
  uint32_t u = ((uint32_t)h) << 16;
  return __builtin_bit_cast(float, u);
}

// async global->LDS, 16B per lane, wave-uniform LDS base + lane*16
__device__ __forceinline__ void gl16(const u16* g, u16* l) {
  __builtin_amdgcn_global_load_lds(
      (const __attribute__((address_space(1))) void*)g,
      (__attribute__((address_space(3))) void*)l, 16, 0, 0);
}

// s_barrier that is also a compiler memory fence
__device__ __forceinline__ void barf() {
  asm volatile("s_barrier" ::: "memory");
}

// ---- T2 LDS XOR-swizzle (rule #21: linear LDS dest + inverse-swz SOURCE + swz READ) ----
// LDS tile rows are 32 u16 = 64B = four 16B slots. Physical slot s at row r holds
// data chunk q = s ^ f(r), f(r) = (r>>1)&3.  gl16 lane l writes row l>>2, slot l&3,
// so lane l must FETCH global chunk (l&3) ^ f(l>>2) = (l&3) ^ ((l>>3)&3).
// (row bases are all multiples of 16, so f(base+d) = (d>>1)&3 — lane-only bits.)
__device__ __forceinline__ int src_chunk(int l) {  // u16 offset of global chunk
  return (((l & 3) ^ ((l >> 3) & 3)) * 8);
}
// reader of fragment row (base + (l&15)) at k-chunk (l>>4): swizzled u16 col offset
__device__ __forceinline__ int rd_koff(int l) {
  return (((l >> 4) ^ (((l & 15) >> 1) & 3)) * 8);
}

// ---------------- input converts (x and x0 in one kernel) ----------------
__global__ void cvt_in2(const float* __restrict__ a, const float* __restrict__ b,
                        u16* __restrict__ da, u16* __restrict__ db, long n8each) {
  long stride = (long)gridDim.x * blockDim.x;
  long total = 2 * n8each;
  for (long i = (long)blockIdx.x * blockDim.x + threadIdx.x; i < total; i += stride) {
    const float* src = (i < n8each) ? a + i * 8 : b + (i - n8each) * 8;
    u16* dst = (i < n8each) ? da + i * 8 : db + (i - n8each) * 8;
    const f32x4* s = (const f32x4*)src;
    f32x4 v0 = s[0], v1 = s[1];
    s16x8 o;
#pragma unroll
    for (int j = 0; j < 4; ++j) o[j] = (short)f2bf(v0[j]);
#pragma unroll
    for (int j = 0; j < 4; ++j) o[4 + j] = (short)f2bf(v1[j]);
    *(s16x8*)dst = o;
  }
}

__global__ void cvt_flat8(const float* __restrict__ src, u16* __restrict__ dst,
                          long n8, float scale) {
  long stride = (long)gridDim.x * blockDim.x;
  for (long i = (long)blockIdx.x * blockDim.x + threadIdx.x; i < n8; i += stride) {
    const f32x4* s = (const f32x4*)(src + i * 8);
    f32x4 a = s[0], b = s[1];
    s16x8 o;
#pragma unroll
    for (int j = 0; j < 4; ++j) o[j] = (short)f2bf(a[j] * scale);
#pragma unroll
    for (int j = 0; j < 4; ++j) o[4 + j] = (short)f2bf(b[j] * scale);
    *(s16x8*)(dst + i * 8) = o;
  }
}

// ---------------- weight prep: all weights -> bf16 (+zero padding) ----------------
__global__ void prep_w(const float* __restrict__ c_wg, const float* __restrict__ c_wp,
                       const float* __restrict__ p_wg, const float* __restrict__ p_wp,
                       const float* __restrict__ c_wt, const float* __restrict__ p_wt,
                       const float* __restrict__ c_ww, const float* __restrict__ p_ww,
                       u16* __restrict__ wcat, u16* __restrict__ wt_c,
                       u16* __restrict__ wt_p, u16* __restrict__ ww_c,
                       u16* __restrict__ ww_p) {
  const int C0 = 1280 * 768 / 4;
  const int C1 = C0 + 384 * 768 / 4;
  const int C2 = C1 + 256 * 768 / 4;
  const int C3 = C2 + 768 * 384 / 4;
  const int C4 = C3 + 768 * 256 / 4;
  int stride = gridDim.x * blockDim.x;
  for (int i = blockIdx.x * blockDim.x + threadIdx.x; i < C4; i += stride) {
    const float* src = nullptr;
    u16* dst;
    if (i < C0) {
      int e = i * 4;
      dst = wcat + e;
      int r = e / 768;
      if (r < 384) src = c_wg + e;
      else if (r < 768) src = c_wp + e - 384 * 768;
      else if (r < 960) src = p_wg + e - 768 * 768;
      else if (r < 1024) src = nullptr;
      else if (r < 1216) src = p_wp + e - 1024 * 768;
      else src = nullptr;
    } else if (i < C1) {
      int e = (i - C0) * 4; dst = wt_c + e; src = c_wt + e;
    } else if (i < C2) {
      int e = (i - C1) * 4; dst = wt_p + e;
      src = (e / 768 < 192) ? p_wt + e : nullptr;
    } else if (i < C3) {
      int e = (i - C2) * 4; dst = ww_c + e; src = c_ww + e;
    } else {
      int e = (i - C3) * 4; dst = ww_p + e;
      int r = e >> 8, c = e & 255;
      src = (c < 192) ? p_ww + r * 192 + c : nullptr;
    }
    s16x4 o;
    if (src) {
      f32x4 v = *(const f32x4*)src;
#pragma unroll
      for (int j = 0; j < 4; ++j) o[j] = (short)f2bf(v[j]);
    } else {
      o = s16x4{0, 0, 0, 0};
    }
    *(s16x4*)dst = o;
  }
}

// biasb[1920] + zero sums[0..3071]
__global__ void prep_b(const float* __restrict__ c_bg, const float* __restrict__ c_bp,
                       const float* __restrict__ p_bg, const float* __restrict__ p_bp,
                       const float* __restrict__ c_bt, const float* __restrict__ p_bt,
                       float* __restrict__ biasb, float* __restrict__ sums) {
  int i = blockIdx.x * blockDim.x + threadIdx.x;
  if (i < 1920) {
    float v = 0.f;
    if (i < 384) v = c_bg[i];
    else if (i < 768) v = c_bp[i - 384];
    else if (i < 960) v = p_bg[i - 768];
    else if (i < 1024) v = 0.f;
    else if (i < 1216) v = p_bp[i - 1024];
    else if (i < 1280) v = 0.f;
    else if (i < 1664) v = c_bt[i - 1280];
    else if (i < 1856) v = p_bt[i - 1664];
    biasb[i] = v;
  } else if (i < 1920 + 3072) {
    sums[i - 1920] = 0.f;
  }
}

// ======== big NT GEMM: 256x256 tile, BK=32, 8 waves, 4-slot LDS ring ========
template <int BIAS, int SUMS>
__global__ __launch_bounds__(512) void gemm_nt_big(
    const u16* __restrict__ A, const u16* __restrict__ B, void* __restrict__ Cv,
    const float* __restrict__ bias, float* __restrict__ sums,
    int ntiles, long lda, long ldb, long ldc, int K,
    long aBatch, long bBatch, long cBatch) {
  __shared__ u16 As[4][256 * 32];  // 4 slots x 16KB
  __shared__ u16 Bs[4][256 * 32];  // total 128KB

  const int bm = blockIdx.x / ntiles;
  const int bn = blockIdx.x % ntiles;
  const int bb = blockIdx.y;
  const int nt = K >> 5;  // K-tiles of 32

  const u16* Ab = A + (long)bb * aBatch + (long)bm * 256 * lda;
  const u16* Bb = B + (long)bb * bBatch + (long)bn * 256 * ldb;

  const int t = threadIdx.x;
  const int w = t >> 6;   // 0..7
  const int l = t & 63;
  const int wr = w >> 2;  // 0..1 (M half)
  const int wc = w & 3;   // 0..3 (N quarter)

  // staging: inst i covers rows [i*128, i*128+128); wave w rows [i*128+w*16, +16)
  // lane l -> row +(l>>2); global chunk pre-swizzled (T2).
  const int srow = w * 16 + (l >> 2);
  const int cg = src_chunk(l);
  const long aoff0 = (long)srow * lda + cg;
  const long aoff1 = (long)(128 + srow) * lda + cg;
  const long boff0 = (long)srow * ldb + cg;
  const long boff1 = (long)(128 + srow) * ldb + cg;

#define STAGE_A(T, BUF)                                   \
  gl16(Ab + aoff0 + (long)(T) * 32, &As[BUF][w * 512]);   \
  gl16(Ab + aoff1 + (long)(T) * 32, &As[BUF][(8 + w) * 512]);
#define STAGE_B(T, BUF)                                   \
  gl16(Bb + boff0 + (long)(T) * 32, &Bs[BUF][w * 512]);   \
  gl16(Bb + boff1 + (long)(T) * 32, &Bs[BUF][(8 + w) * 512]);

  f32x4 acc[8][4] = {};

  // prologue: stage tiles 0,1,2 (12 gl16/wave); wait tile 0 (keep 8 in flight)
  STAGE_A(0, 0); STAGE_B(0, 0);
  if (nt > 1) { STAGE_A(1, 1); STAGE_B(1, 1); }
  if (nt > 2) { STAGE_A(2, 2); STAGE_B(2, 2); }
  if (nt > 2)      asm volatile("s_waitcnt vmcnt(8)" ::: "memory");
  else if (nt > 1) asm volatile("s_waitcnt vmcnt(4)" ::: "memory");
  else             asm volatile("s_waitcnt vmcnt(0)" ::: "memory");
  barf();

  const int koff = rd_koff(l);          // swizzled u16 k-offset within row
  const int ar = wr * 128 + (l & 15);   // A row base for fragments
  const int br = wc * 64 + (l & 15);    // B row base

  for (int tt = 0; tt < nt; ++tt) {
    const int cur = tt & 3;
    const int pf = (tt + 3) & 3;
    const bool do_pf = (tt + 3) < nt;

    // ---- phase 0: B frags + A frags(m0..3); stage A of tile tt+3 ----
    bf16x8 bfr[4], af[4];
#pragma unroll
    for (int ni = 0; ni < 4; ++ni)
      bfr[ni] = __builtin_bit_cast(
          bf16x8, *(const s16x8*)(&Bs[cur][(br + ni * 16) * 32 + koff]));
#pragma unroll
    for (int mi = 0; mi < 4; ++mi)
      af[mi] = __builtin_bit_cast(
          bf16x8, *(const s16x8*)(&As[cur][(ar + mi * 16) * 32 + koff]));
    if (do_pf) { STAGE_A(tt + 3, pf); }
    barf();
    __builtin_amdgcn_s_setprio(1);
#pragma unroll
    for (int mi = 0; mi < 4; ++mi)
#pragma unroll
      for (int ni = 0; ni < 4; ++ni)
        acc[mi][ni] = __builtin_amdgcn_mfma_f32_16x16x32_bf16(
            af[mi], bfr[ni], acc[mi][ni], 0, 0, 0);
    __builtin_amdgcn_s_setprio(0);
    barf();

    // ---- phase 1: A frags(m4..7); stage B of tile tt+3 ----
    bf16x8 ag[4];
#pragma unroll
    for (int mi = 0; mi < 4; ++mi)
      ag[mi] = __builtin_bit_cast(
          bf16x8, *(const s16x8*)(&As[cur][(ar + 64 + mi * 16) * 32 + koff]));
    if (do_pf) { STAGE_B(tt + 3, pf); }
    barf();
    __builtin_amdgcn_s_setprio(1);
#pragma unroll
    for (int mi = 0; mi < 4; ++mi)
#pragma unroll
      for (int ni = 0; ni < 4; ++ni)
        acc[4 + mi][ni] = __builtin_amdgcn_mfma_f32_16x16x32_bf16(
            ag[mi], bfr[ni], acc[4 + mi][ni], 0, 0, 0);
    __builtin_amdgcn_s_setprio(0);
    // counted wait for NEXT tile (retire tt+1's 4 loads; keep rest in flight)
    if (tt + 4 <= nt)      asm volatile("s_waitcnt vmcnt(8)" ::: "memory");
    else if (tt + 3 == nt) asm volatile("s_waitcnt vmcnt(4)" ::: "memory");
    else if (tt + 2 == nt) asm volatile("s_waitcnt vmcnt(0)" ::: "memory");
    barf();
  }
#undef STAGE_A
#undef STAGE_B
  __builtin_amdgcn_sched_barrier(0);

  const long crow0 = (long)bm * 256 + wr * 128;
  const long ccol0 = (long)bn * 256 + wc * 64;
  u16* C = (u16*)Cv + (long)bb * cBatch;
#pragma unroll
  for (int mi = 0; mi < 8; ++mi)
#pragma unroll
    for (int j = 0; j < 4; ++j) {
      long row = crow0 + mi * 16 + (l >> 4) * 4 + j;
      float rb = (BIAS == 1) ? bias[row] : 0.f;
#pragma unroll
      for (int ni = 0; ni < 4; ++ni) {
        long col = ccol0 + ni * 16 + (l & 15);
        C[row * ldc + col] = f2bf(acc[mi][ni][j] + rb);
      }
    }

  if (SUMS) {
#pragma unroll
    for (int ni = 0; ni < 4; ++ni) {
      float s = 0.f, q = 0.f;
#pragma unroll
      for (int mi = 0; mi < 8; ++mi)
#pragma unroll
        for (int j = 0; j < 4; ++j) {
          float v = acc[mi][ni][j];
          s += v;
          q += v * v;
        }
      s += __shfl_xor(s, 16);
      q += __shfl_xor(q, 16);
      s += __shfl_xor(s, 32);
      q += __shfl_xor(q, 32);
      if (l < 16) {
        long col = ccol0 + ni * 16 + l;
        atomicAdd(&sums[col], s);
        atomicAdd(&sums[768 + col], q);
      }
    }
  }
}

// ---------------- generic NT GEMM (128x128, 4 waves) — small/odd shapes ----------------
template <int BIAS, int OUT_ATOMIC, int SUMS>
__global__ __launch_bounds__(256) void gemm_nt(
    const u16* __restrict__ A, const u16* __restrict__ B, void* __restrict__ Cv,
    const float* __restrict__ bias, float* __restrict__ sums,
    int ntiles, long lda, long ldb, long ldc, int K,
    long aBatch, long bBatch, long cBatch) {
  __shared__ u16 As[2][128 * 32];
  __shared__ u16 Bs[2][128 * 32];

  const int bm = blockIdx.x / ntiles;
  const int bn = blockIdx.x % ntiles;
  const int bb = blockIdx.y;
  const int kChunk = K / gridDim.z;
  const long k0base = (long)blockIdx.z * kChunk;
  const int nt = kChunk >> 5;

  const u16* Ab = A + (long)bb * aBatch + (long)bm * 128 * lda + k0base;
  const u16* Bb = B + (long)bb * bBatch + (long)bn * 128 * ldb + k0base;

  const int t = threadIdx.x;
  const int w = t >> 6;
  const int l = t & 63;
  const int wr = w >> 1, wc = w & 1;

  const int cg = src_chunk(l);
  const long aoff = (long)(32 * w + (l >> 2)) * lda + cg;
  const long boff = (long)(32 * w + (l >> 2)) * ldb + cg;

  f32x4 acc[4][4] = {};

  gl16(Ab + aoff, &As[0][(32 * w) * 32]);
  gl16(Ab + aoff + 16 * lda, &As[0][(32 * w + 16) * 32]);
  gl16(Bb + boff, &Bs[0][(32 * w) * 32]);
  gl16(Bb + boff + 16 * ldb, &Bs[0][(32 * w + 16) * 32]);
  if (nt > 1) {
    gl16(Ab + aoff + 32, &As[1][(32 * w) * 32]);
    gl16(Ab + aoff + 16 * lda + 32, &As[1][(32 * w + 16) * 32]);
    gl16(Bb + boff + 32, &Bs[1][(32 * w) * 32]);
    gl16(Bb + boff + 16 * ldb + 32, &Bs[1][(32 * w + 16) * 32]);
  }

  const int koff = rd_koff(l);

  for (int tt = 0; tt < nt; ++tt) {
    const int cur = tt & 1;
    if (tt + 1 < nt)
      asm volatile("s_waitcnt vmcnt(4)" ::: "memory");
    else
      asm volatile("s_waitcnt vmcnt(0)" ::: "memory");
    __builtin_amdgcn_s_barrier();

    bf16x8 af[4], bfr[4];
#pragma unroll
    for (int mi = 0; mi < 4; ++mi)
      af[mi] = __builtin_bit_cast(
          bf16x8, *(const s16x8*)(&As[cur][(wr * 64 + mi * 16 + (l & 15)) * 32 + koff]));
#pragma unroll
    for (int ni = 0; ni < 4; ++ni)
      bfr[ni] = __builtin_bit_cast(
          bf16x8, *(const s16x8*)(&Bs[cur][(wc * 64 + ni * 16 + (l & 15)) * 32 + koff]));
#pragma unroll
    for (int mi = 0; mi < 4; ++mi)
#pragma unroll
      for (int ni = 0; ni < 4; ++ni)
        acc[mi][ni] = __builtin_amdgcn_mfma_f32_16x16x32_bf16(
            af[mi], bfr[ni], acc[mi][ni], 0, 0, 0);

    __builtin_amdgcn_s_barrier();
    if (tt + 2 < nt) {
      const long ko = (long)(tt + 2) * 32;
      gl16(Ab + aoff + ko, &As[cur][(32 * w) * 32]);
      gl16(Ab + aoff + 16 * lda + ko, &As[cur][(32 * w + 16) * 32]);
      gl16(Bb + boff + ko, &Bs[cur][(32 * w) * 32]);
      gl16(Bb + boff + 16 * ldb + ko, &Bs[cur][(32 * w + 16) * 32]);
    }
  }
  __builtin_amdgcn_sched_barrier(0);

  const long crow0 = (long)bm * 128 + wr * 64;
  const long ccol0 = (long)bn * 128 + wc * 64;

  if (OUT_ATOMIC) {
    float* C = (float*)Cv + (long)bb * cBatch;
#pragma unroll
    for (int mi = 0; mi < 4; ++mi)
#pragma unroll
      for (int j = 0; j < 4; ++j) {
        long row = crow0 + mi * 16 + (l >> 4) * 4 + j;
#pragma unroll
        for (int ni = 0; ni < 4; ++ni) {
          long col = ccol0 + ni * 16 + (l & 15);
          atomicAdd(&C[row * ldc + col], acc[mi][ni][j]);
        }
      }
  } else {
    u16* C = (u16*)Cv + (long)bb * cBatch;
#pragma unroll
    for (int mi = 0; mi < 4; ++mi)
#pragma unroll
      for (int j = 0; j < 4; ++j) {
        long row = crow0 + mi * 16 + (l >> 4) * 4 + j;
        float rb = (BIAS == 1) ? bias[row] : 0.f;
#pragma unroll
        for (int ni = 0; ni < 4; ++ni) {
          long col = ccol0 + ni * 16 + (l & 15);
          float cb = (BIAS == 2) ? bias[col] : 0.f;
          C[row * ldc + col] = f2bf(acc[mi][ni][j] + rb + cb);
        }
      }
  }

  if (SUMS) {
#pragma unroll
    for (int ni = 0; ni < 4; ++ni) {
      float s = 0.f, q = 0.f;
#pragma unroll
      for (int mi = 0; mi < 4; ++mi)
#pragma unroll
        for (int j = 0; j < 4; ++j) {
          float v = acc[mi][ni][j];
          s += v;
          q += v * v;
        }
      s += __shfl_xor(s, 16);
      q += __shfl_xor(q, 16);
      s += __shfl_xor(s, 32);
      q += __shfl_xor(q, 32);
      if (l < 16) {
        long col = ccol0 + ni * 16 + l;
        atomicAdd(&sums[col], s);
        atomicAdd(&sums[768 + col], q);
      }
    }
  }
}

// ---------------- BN ----------------
__global__ void bn_stats(const float* __restrict__ sums, const float* __restrict__ gamma,
                         const float* __restrict__ beta, float* __restrict__ stats,
                         float invN) {
  int c = threadIdx.x;
  float mu = sums[c] * invN;
  float var = sums[768 + c] * invN - mu * mu;
  float sc = gamma[c] * rsqrtf(var + 1e-5f);
  stats[c] = sc;
  stats[768 + c] = beta[c] - mu * sc;
}

template <int OUT_F32>
__global__ void bn_apply(const u16* __restrict__ pre, const u16* __restrict__ resid,
                         const float* __restrict__ stats, void* __restrict__ out,
                         long n8) {
  long stride = (long)gridDim.x * blockDim.x;
  for (long i = (long)blockIdx.x * blockDim.x + threadIdx.x; i < n8; i += stride) {
    long base = i * 8;
    int c = (int)(base % 768);
    f32x4 sc0 = *(const f32x4*)(stats + c);
    f32x4 sc1 = *(const f32x4*)(stats + c + 4);
    f32x4 sh0 = *(const f32x4*)(stats + 768 + c);
    f32x4 sh1 = *(const f32x4*)(stats + 768 + c + 4);
    s16x8 p = *(const s16x8*)(pre + base);
    s16x8 rv = *(const s16x8*)(resid + base);
    float o[8];
#pragma unroll
    for (int j = 0; j < 4; ++j)
      o[j] = bf2f((u16)p[j]) * sc0[j] + sh0[j] + bf2f((u16)rv[j]);
#pragma unroll
    for (int j = 0; j < 4; ++j)
      o[4 + j] = bf2f((u16)p[4 + j]) * sc1[j] + sh1[j] + bf2f((u16)rv[4 + j]);
    if (OUT_F32) {
      f32x4 o0, o1;
#pragma unroll
      for (int j = 0; j < 4; ++j) { o0[j] = o[j]; o1[j] = o[4 + j]; }
      f32x4* op = (f32x4*)((float*)out + base);
      op[0] = o0;
      op[1] = o1;
    } else {
      s16x8 ov;
#pragma unroll
      for (int j = 0; j < 8; ++j) ov[j] = (short)f2bf(o[j]);
      *(s16x8*)((u16*)out + base) = ov;
    }
  }
}

extern "C" void kernel_launch(void* const* d_in, const int* in_sizes, int n_in,
                              void* d_out, int out_size, void* d_ws, size_t ws_size,
                              hipStream_t stream) {
  const float* x = (const float*)d_in[0];
  const float* x0 = (const float*)d_in[1];
  const float* c_wg = (const float*)d_in[2];
  const float* c_bg = (const float*)d_in[3];
  const float* c_wt = (const float*)d_in[4];
  const float* c_bt = (const float*)d_in[5];
  const float* c_wp = (const float*)d_in[6];
  const float* c_bp = (const float*)d_in[7];
  const float* c_ww = (const float*)d_in[8];
  const float* c_gamma = (const float*)d_in[10];
  const float* c_beta = (const float*)d_in[11];
  const float* p_wg = (const float*)d_in[12];
  const float* p_bg = (const float*)d_in[13];
  const float* p_wt = (const float*)d_in[14];
  const float* p_bt = (const float*)d_in[15];
  const float* p_wp = (const float*)d_in[16];
  const float* p_bp = (const float*)d_in[17];
  const float* p_ww = (const float*)d_in[18];
  const float* p_gamma = (const float*)d_in[20];
  const float* p_beta = (const float*)d_in[21];

  char* ws = (char*)d_ws;
  const long NT = 32768;
  u16* xbf = (u16*)(ws + 0);
  u16* x0bf = (u16*)(ws + 50331648);
  u16* th = (u16*)(ws + 50331648);
  float* kvf_c = (float*)(ws + 75497472);
  float* kvf_p = (float*)(ws + 80216064);
  u16* kvb = (u16*)(ws + 82313216);
  u16* kvwT = (u16*)(ws + 84672512);
  u16* gphT = (u16*)(ws + 100663296);
  u16* wcat = (u16*)(ws + 184549376);
  u16* wt_c = (u16*)(ws + 186515456);
  u16* wt_p = (u16*)(ws + 187105280);
  u16* ww_c = (u16*)(ws + 187498496);
  u16* ww_p = (u16*)(ws + 188088320);
  float* biasb = (float*)(ws + 188481536);
  float* sums = (float*)(ws + 188489216);
  float* stats = (float*)(ws + 188501504);
  u16* zbf = xbf;
  u16* pre = gphT;

  // ---- prep ----
  cvt_in2<<<4096, 256, 0, stream>>>(x, x0, xbf, x0bf, NT * 768 / 8);
  prep_w<<<480, 256, 0, stream>>>(c_wg, c_wp, p_wg, p_wp, c_wt, p_wt, c_ww, p_ww,
                                  wcat, wt_c, wt_p, ww_c, ww_p);
  prep_b<<<20, 256, 0, stream>>>(c_bg, c_bp, p_bg, p_bp, c_bt, p_bt, biasb, sums);

  // ---- fused gphT[1280][32768] = Wcat @ x0^T (+row bias), 256^2 pipeline ----
  gemm_nt_big<1, 0><<<dim3(5 * 128, 1, 1), 512, 0, stream>>>(
      wcat, x0bf, gphT, biasb, nullptr, 128, 768, 768, 32768, 768, 0, 0, 0);
  hipMemsetAsync(kvf_c, 0, 4718592 + 2097152, stream);

  // ================= CNL (D=384) =================
  gemm_nt<2, 0, 0><<<dim3(256 * 3, 1, 1), 256, 0, stream>>>(
      xbf, wt_c, th, biasb + 1280, nullptr, 3, 768, 768, 384, 768, 0, 0, 0);
  gemm_nt<0, 1, 0><<<dim3(9, 8, 8), 256, 0, stream>>>(
      gphT + (long)384 * 32768, gphT, kvf_c, nullptr, nullptr, 3, 32768, 32768,
      384, 4096, 4096, 4096, (long)384 * 384);
  cvt_flat8<<<576, 256, 0, stream>>>(kvf_c, kvb, (long)8 * 384 * 384 / 8, 1.f / 4096.f);
  gemm_nt<0, 0, 0><<<dim3(18, 8, 1), 256, 0, stream>>>(
      ww_c, kvb, kvwT, nullptr, nullptr, 3, 384, 384, 384, 384, 0,
      (long)384 * 384, (long)768 * 384);
  gemm_nt_big<0, 1><<<dim3(48, 8, 1), 512, 0, stream>>>(
      th, kvwT, pre, nullptr, sums, 3, 384, 384, 768, 384, (long)4096 * 384,
      (long)768 * 384, (long)4096 * 768);
  bn_stats<<<1, 768, 0, stream>>>(sums, c_gamma, c_beta, stats, 1.f / 32768.f);
  bn_apply<0><<<2048, 256, 0, stream>>>(pre, xbf, stats, zbf, NT * 768 / 8);

  // ================= PNL (D=192, padded to 256) =================
  gemm_nt<2, 0, 0><<<dim3(256 * 2, 1, 1), 256, 0, stream>>>(
      zbf, wt_p, th, biasb + 1664, nullptr, 2, 768, 768, 256, 768, 0, 0, 0);
  gemm_nt<0, 1, 0><<<dim3(4, 8, 8), 256, 0, stream>>>(
      gphT + (long)1024 * 32768, gphT + (long)768 * 32768, kvf_p, nullptr, nullptr,
      2, 32768, 32768, 256, 4096, 4096, 4096, (long)256 * 256);
  cvt_flat8<<<256, 256, 0, stream>>>(kvf_p, kvb, (long)8 * 256 * 256 / 8, 1.f / 4096.f);
  gemm_nt<0, 0, 0><<<dim3(12, 8, 1), 256, 0, stream>>>(
      ww_p, kvb, kvwT, nullptr, nullptr, 2, 256, 256, 256, 256, 0,
      (long)256 * 256, (long)768 * 256);
  gemm_nt_big<0, 1><<<dim3(48, 8, 1), 512, 0, stream>>>(
      th, kvwT, pre, nullptr, sums + 1536, 3, 256, 256, 768, 256, (long)4096 * 256,
      (long)768 * 256, (long)4096 * 768);
  bn_stats<<<1, 768, 0, stream>>>(sums + 1536, p_gamma, p_beta, stats, 1.f / 32768.f);
  bn_apply<1><<<2048, 256, 0, stream>>>(pre, zbf, stats, (float*)d_out, NT * 768 / 8);
}